// Round 14
// baseline (191.481 us; speedup 1.0000x reference)
//
#include <hip/hip_runtime.h>
#include <hip/hip_bf16.h>

using bf16 = __hip_bfloat16;

typedef __bf16 bf16x8 __attribute__((ext_vector_type(8)));
typedef __bf16 bf16x4v __attribute__((ext_vector_type(4)));
typedef float  float4v __attribute__((ext_vector_type(4)));
typedef unsigned short u16x8 __attribute__((ext_vector_type(8)));

#define MFMA16x16x32(a, b, c) __builtin_amdgcn_mfma_f32_16x16x32_bf16((a), (b), (c), 0, 0, 0)

#if __has_builtin(__builtin_amdgcn_exp2f)
#define EXP2F(x) __builtin_amdgcn_exp2f(x)
#else
#define EXP2F(x) exp2f(x)
#endif

#define T_SEQ 2048
#define NHEAD 16
#define CDIM  1024
#define HD3   3072

// async global->LDS, 16B per lane. LDS dest must be wave-uniform base + lane*16.
__device__ __forceinline__ void async_copy16(const void* g, void* l) {
    __builtin_amdgcn_global_load_lds(
        (__attribute__((address_space(1))) unsigned int*)g,
        (__attribute__((address_space(3))) unsigned int*)l,
        16, 0, 0);
}

// ---------------------------------------------------------------------------
// Convert + dtype detection, VECTORIZED (round-8 proven): float4 loads +
// bf16x4 stores, three branch-free per-region loops. Dedicated conversion
// reads x ONCE (fusing into gemm1 tripled its FETCH -- round 12). Each block
// re-detects (L2-hit); block 0 publishes flag[0]. flag=1 -> fp32 input.
// ---------------------------------------------------------------------------
__global__ __launch_bounds__(256) void convert_detect_kernel(
    const float* __restrict__ x, const float* __restrict__ wa,
    const float* __restrict__ wp,
    bf16* __restrict__ xb, bf16* __restrict__ wab, bf16* __restrict__ wpb,
    int* __restrict__ flag)
{
    __shared__ int red[256];
    const u16x8* xs8 = (const u16x8*)x;
    int cnt = 0;
    for (int i = threadIdx.x; i < 2048; i += 256) {
        const u16x8 v = xs8[i];
#pragma unroll
        for (int t = 0; t < 8; ++t) {
            const int e = (v[t] >> 7) & 0xFF;
            if (e == 0xFF || (e != 0 && e < 0x60)) cnt++;
        }
    }
    red[threadIdx.x] = cnt;
    __syncthreads();
    for (int s = 128; s > 0; s >>= 1) {
        if (threadIdx.x < s) red[threadIdx.x] += red[threadIdx.x + s];
        __syncthreads();
    }
    const int isf32 = (red[0] > 100) ? 1 : 0;
    if (blockIdx.x == 0 && threadIdx.x == 0) flag[0] = isf32;
    if (!isf32) return;

    const int gid    = blockIdx.x * 256 + threadIdx.x;
    const int stride = gridDim.x * 256;
    const float4v* x4  = (const float4v*)x;    // 1048576 float4
    const float4v* wa4 = (const float4v*)wa;   //  786432 float4
    const float4v* wp4 = (const float4v*)wp;   //  262144 float4
    bf16x4v* xb4  = (bf16x4v*)xb;
    bf16x4v* wab4 = (bf16x4v*)wab;
    bf16x4v* wpb4 = (bf16x4v*)wpb;

    for (int i = gid; i < 1048576; i += stride) {
        const float4v v = x4[i];
        bf16x4v o;
#pragma unroll
        for (int t = 0; t < 4; ++t) o[t] = (__bf16)v[t];
        xb4[i] = o;
    }
    for (int i = gid; i < 786432; i += stride) {
        const float4v v = wa4[i];
        bf16x4v o;
#pragma unroll
        for (int t = 0; t < 4; ++t) o[t] = (__bf16)v[t];
        wab4[i] = o;
    }
    for (int i = gid; i < 262144; i += stride) {
        const float4v v = wp4[i];
        bf16x4v o;
#pragma unroll
        for (int t = 0; t < 4; ++t) o[t] = (__bf16)v[t];
        wpb4[i] = o;
    }
}

// ---------------------------------------------------------------------------
// NT GEMM, BK=64, XOR-swizzled async staging. Round-14: TRIPLE-BUFFERED LDS
// with COUNTED vmcnt (T4): stage tile t+2 while computing t; at the barrier
// wait only vmcnt(6) -- tile t+2's 6 loads/thread stay in flight, tile t+1
// (everything older) is guaranteed complete. Depth-2 latency cover vs the
// round-10 2-buffer depth-1 (gemm1 was MfmaUtil 21.8%, latency-bound at
// ~2 blocks/CU). Tail iterations (nothing newer in flight) drain vmcnt(0).
// Reads of buf t%3 all precede the barrier, so re-staging it at t+1 is safe.
// JF = per-wave N fragments (JF=2 -> BN=64; vmcnt(6) literal assumes JF=2).
// swz: bijective XCD remap (grid %8==0 required).
// scale_q: multiply (acc+bias) by 0.125*log2e for cols < 1024 (q-columns).
// ---------------------------------------------------------------------------
template<int JF>
__global__ __launch_bounds__(256) void gemm_nt_lds_t(
    const void* __restrict__ Araw, const bf16* __restrict__ Aconv,
    const void* __restrict__ Braw, const bf16* __restrict__ Bconv,
    const void* __restrict__ biasraw, void* __restrict__ Cv,
    int M, int N, int K, const int* __restrict__ flag, int is_final,
    int scale_q, int swz)
{
    static_assert(JF == 2, "vmcnt(6) literal assumes 4 A + 2 B loads/thread");
    const bool f32 = (flag[0] != 0);
    const bf16* A = f32 ? Aconv : (const bf16*)Araw;
    const bf16* B = f32 ? Bconv : (const bf16*)Braw;

    __shared__ bf16 As[3][128 * 64];
    __shared__ bf16 Bs[3][JF * 32 * 64];

    const int tid  = threadIdx.x;
    const int lane = tid & 63;
    const int wave = tid >> 6;
    const int wm = wave & 1, wn = wave >> 1;
    const int c = lane & 15, g = lane >> 4;

    int bx = blockIdx.x, by = blockIdx.y;
    if (swz) {
        const int nwg = gridDim.x * gridDim.y;
        const int lin = by * gridDim.x + bx;
        const int nl  = (lin & 7) * (nwg >> 3) + (lin >> 3);
        bx = nl % gridDim.x;
        by = nl / gridDim.x;
    }
    const int bm = bx * 128;
    const int bn = by * (JF * 32);

    const int srow = tid >> 3;
    const int slc  = ((tid & 7) ^ (srow & 7)) * 8;
    const bf16* gA = A + (size_t)(bm + srow) * K + slc;
    const bf16* gB = B + (size_t)(bn + srow) * K + slc;

    float4v acc[4][JF] = {};

    const int nk = K >> 6;

    // stage tile t (64 k-cols) into LDS buffer buf: 4 A + JF B loads/thread
    auto stage = [&](int t, int buf) {
#pragma unroll
        for (int q = 0; q < 4; ++q)
            async_copy16(gA + t * 64 + (size_t)(q * 32) * K,
                         &As[buf][q * 2048 + tid * 8]);
#pragma unroll
        for (int q = 0; q < JF; ++q)
            async_copy16(gB + t * 64 + (size_t)(q * 32) * K,
                         &Bs[buf][q * 2048 + tid * 8]);
    };

    // prologue: tiles 0 and 1 in flight; wait until only tile1's 6 remain
    stage(0, 0);
    stage(1, 1);
    asm volatile("s_waitcnt vmcnt(6)" ::: "memory");
    __builtin_amdgcn_s_barrier();

    int b = 0;                            // buffer of tile t (t % 3)
    for (int t = 0; t < nk; ++t) {
        const bool deep = (t + 2 < nk);
        if (deep) stage(t + 2, (b + 2 >= 3) ? b - 1 : b + 2);

#pragma unroll
        for (int kk = 0; kk < 2; ++kk) {
            bf16x8 af[4], bfr[JF];
#pragma unroll
            for (int i = 0; i < 4; ++i)
                af[i]  = *(const bf16x8*)&As[b][(wm * 64 + i * 16 + c) * 64 +
                                               (((kk * 4 + g) ^ (c & 7)) * 8)];
#pragma unroll
            for (int j = 0; j < JF; ++j)
                bfr[j] = *(const bf16x8*)&Bs[b][(wn * (JF * 16) + j * 16 + c) * 64 +
                                               (((kk * 4 + g) ^ (c & 7)) * 8)];
#pragma unroll
            for (int i = 0; i < 4; ++i)
#pragma unroll
                for (int j = 0; j < JF; ++j)
                    acc[i][j] = MFMA16x16x32(af[i], bfr[j], acc[i][j]);
        }

        // counted wait: tile t+1 complete (only tile t+2's 6 may remain);
        // tail (no tile t+2 issued): full drain.
        if (deep) asm volatile("s_waitcnt vmcnt(6)" ::: "memory");
        else      asm volatile("s_waitcnt vmcnt(0)" ::: "memory");
        __builtin_amdgcn_s_barrier();

        b = (b == 2) ? 0 : b + 1;
    }

    const bool f32o = is_final && f32;
    bf16*  Cb = (bf16*)Cv;
    float* Cf = (float*)Cv;

#pragma unroll
    for (int i = 0; i < 4; ++i) {
        const int row = bm + wm * 64 + i * 16 + g * 4;
#pragma unroll
        for (int j = 0; j < JF; ++j) {
            const int col = bn + wn * (JF * 16) + j * 16 + c;
            const float bv = f32 ? ((const float*)biasraw)[col]
                                 : __bfloat162float(((const bf16*)biasraw)[col]);
            const float sc = (scale_q && col < 1024) ? 0.18033688f : 1.0f;
            if (f32o) {
#pragma unroll
                for (int t = 0; t < 4; ++t)
                    Cf[(size_t)(row + t) * N + col] = (acc[i][j][t] + bv) * sc;
            } else {
#pragma unroll
                for (int t = 0; t < 4; ++t)
                    Cb[(size_t)(row + t) * N + col] =
                        __float2bfloat16((acc[i][j][t] + bv) * sc);
            }
        }
    }
}

// ---------------------------------------------------------------------------
// MFMA flash attention v9 (round-5/7/8/10/13 proven, unchanged): heavy/light
// pairing + bh->XCD locality, 8 waves x 16 queries per 128-q block (512
// threads). Staging role-split: waves 0-3 stage K (async), waves 4-7 stage V.
// ---------------------------------------------------------------------------
__global__ __launch_bounds__(512) void attn_mfma(
    const bf16* __restrict__ qkv, bf16* __restrict__ y)
{
    __shared__ __bf16 Ks[2][128 * 64];   // [buf][key][dim], chunk ^ (key&7)
    __shared__ __bf16 Vt[2][64 * 128];   // [buf][dim][kappa], chunk ^ (dim&7)

    const int tid  = threadIdx.x;
    const int lane = tid & 63;
    const int w    = tid >> 6;           // 0..7
    const int c    = lane & 15;
    const int g    = lane >> 4;

    // decode: i = role*256 + ((j*4 + bh_hi)<<3 | bh_lo); XCD = i%8 = bh&7
    const int i    = blockIdx.x;
    const int role = i >> 8;             // 0 = heavy, 1 = light
    const int bhl  = i & 7;
    const int t5   = (i & 255) >> 3;     // 0..31
    const int j    = t5 >> 2;            // 0..7
    const int bh   = ((t5 & 3) << 3) | bhl;
    const int qblk = role ? j : (15 - j);
    const int bb   = bh >> 4;
    const int h    = bh & 15;
    const size_t base = (size_t)bb * T_SEQ * HD3 + (size_t)h * 64;

    // staging indices (st = index within the staging half)
    const bool kstage = (tid < 256);
    const int st   = tid & 255;
    const int krow = st >> 3;                        // K: 0..31 (+ q*32)
    const int klc  = ((st & 7) ^ (krow & 7)) * 8;    // K: logical dim col
    const int kq   = st & 31;                        // V: key group
    const int dgv  = st >> 5;                        // V: dim group 0..7
    const int vchunk = (kq >> 3) * 4 + (kq & 3);
    const int vlow   = ((kq >> 2) & 1) * 4;

    const bf16* kgbase = qkv + base + 1024;
    const bf16* vgbase = qkv + base + 2048;

    bf16x8 ones;
#pragma unroll
    for (int ii = 0; ii < 8; ++ii) ones[ii] = (__bf16)1.0f;

    const int q0 = qblk * 128;
    const int qw = q0 + w * 16;          // wave query origin (16 q per wave)

    // Q B-fragment (pre-scaled by 0.125*log2e in gemm1 epilogue)
    bf16x8 qf[2];
#pragma unroll
    for (int kf2 = 0; kf2 < 2; ++kf2)
        qf[kf2] = *(const bf16x8*)(qkv + base
            + (size_t)(qw + c) * HD3 + kf2 * 32 + g * 8);

    float4v o[4] = {};
    float4v ol = {};                     // lsum via ones-MFMA

    // ---- prologue: stage tile 0 into buf 0 ----
    if (kstage) {
#pragma unroll
        for (int q = 0; q < 4; ++q)
            async_copy16(kgbase + (size_t)(q * 32 + krow) * HD3 + klc,
                         &Ks[0][q * 2048 + st * 8]);
    } else {
        bf16x8 vr[4];
#pragma unroll
        for (int r = 0; r < 4; ++r)
            vr[r] = *(const bf16x8*)(vgbase + (size_t)(kq * 4 + r) * HD3 + dgv * 8);
#pragma unroll
        for (int jj = 0; jj < 8; ++jj) {
            const int d = dgv * 8 + jj;
            bf16x4v pk;
#pragma unroll
            for (int r = 0; r < 4; ++r) pk[r] = vr[r][jj];
            *(bf16x4v*)&Vt[0][d * 128 + ((vchunk ^ (d & 7)) << 3) + vlow] = pk;
        }
    }
    __syncthreads();

    int b = 0;
    for (int kt = 0; kt <= q0; kt += 128, b ^= 1) {
        const bool more = (kt + 128 <= q0);
        bf16x8 vr[4];
        if (more) {
            if (kstage) {
#pragma unroll
                for (int q = 0; q < 4; ++q)
                    async_copy16(kgbase + (size_t)(kt + 128 + q * 32 + krow) * HD3 + klc,
                                 &Ks[b ^ 1][q * 2048 + st * 8]);
            } else {
#pragma unroll
                for (int r = 0; r < 4; ++r)
                    vr[r] = *(const bf16x8*)(vgbase + (size_t)(kt + 128 + kq * 4 + r) * HD3 + dgv * 8);
            }
        }

#pragma unroll
        for (int hf = 0; hf < 2; ++hf) {
            if (kt + hf * 64 > qw + 15) continue;   // whole half masked for wave

            // ---- S^T = K Q^T over 64 keys x 16 queries ----
            float4v sacc[4] = {};
            __builtin_amdgcn_s_setprio(1);
#pragma unroll
            for (int jb = 0; jb < 4; ++jb) {
                const int key = hf * 64 + jb * 16 + c;
                bf16x8 a0 = *(const bf16x8*)&Ks[b][key * 64 + ((g ^ (c & 7)) * 8)];
                bf16x8 a1 = *(const bf16x8*)&Ks[b][key * 64 + (((4 + g) ^ (c & 7)) * 8)];
                sacc[jb] = MFMA16x16x32(a0, qf[0], sacc[jb]);
                sacc[jb] = MFMA16x16x32(a1, qf[1], sacc[jb]);
            }
            __builtin_amdgcn_s_setprio(0);

            // ---- mask + exp2 + pack P (registers only) ----
            bf16x8 pf[2];
            {
                if (kt + hf * 64 + 63 > qw) {
                    const int query = qw + c;
#pragma unroll
                    for (int jb = 0; jb < 4; ++jb) {
                        const int kb = kt + hf * 64 + jb * 16 + g * 4;
#pragma unroll
                        for (int t = 0; t < 4; ++t)
                            if (kb + t > query) sacc[jb][t] = -1e30f;
                    }
                }
#pragma unroll
                for (int jb = 0; jb < 4; ++jb)
#pragma unroll
                    for (int t = 0; t < 4; ++t)
                        sacc[jb][t] = EXP2F(sacc[jb][t]);
#pragma unroll
                for (int lkf = 0; lkf < 2; ++lkf) {
                    bf16x8 pk;
#pragma unroll
                    for (int jj = 0; jj < 8; ++jj)
                        pk[jj] = (__bf16)sacc[lkf * 2 + (jj >> 2)][jj & 3];
                    pf[lkf] = pk;
                }
            }

            // ---- O^T += V^T P ; lsum += 1^T P (this half) ----
            __builtin_amdgcn_s_setprio(1);
#pragma unroll
            for (int lkf = 0; lkf < 2; ++lkf) {
                const int kf = hf * 2 + lkf;
                ol = MFMA16x16x32(ones, pf[lkf], ol);
#pragma unroll
                for (int dn = 0; dn < 4; ++dn) {
                    const int d = dn * 16 + c;
                    bf16x8 vf = *(const bf16x8*)
                        &Vt[b][d * 128 + (((kf * 4 + g) ^ (d & 7)) << 3)];
                    o[dn] = MFMA16x16x32(vf, pf[lkf], o[dn]);
                }
            }
            __builtin_amdgcn_s_setprio(0);
        }

        if (more && !kstage) {
#pragma unroll
            for (int jj = 0; jj < 8; ++jj) {
                const int d = dgv * 8 + jj;
                bf16x4v pk;
#pragma unroll
                for (int r = 0; r < 4; ++r) pk[r] = vr[r][jj];
                *(bf16x4v*)&Vt[b ^ 1][d * 128 + ((vchunk ^ (d & 7)) << 3) + vlow] = pk;
            }
        }
        __syncthreads();
    }

    // ---- store: lane holds query q (col c), dims dn*16+g*4+t ----
    {
        const float linv = 1.f / ol.x;
        const int q = qw + c;
        const size_t yb = ((size_t)bb * T_SEQ + q) * CDIM + h * 64;
#pragma unroll
        for (int dn = 0; dn < 4; ++dn) {
            bf16x4v ov;
#pragma unroll
            for (int t = 0; t < 4; ++t)
                ov[t] = (__bf16)(o[dn][t] * linv);
            *(bf16x4v*)&y[yb + dn * 16 + g * 4] = ov;
        }
    }
}

// ---------------------------------------------------------------------------
extern "C" void kernel_launch(void* const* d_in, const int* in_sizes, int n_in,
                              void* d_out, int out_size, void* d_ws, size_t ws_size,
                              hipStream_t stream)
{
    const int M = 4096;   // B*T
    char* ws = (char*)d_ws;

    // Footprint identical to the proven baseline: max offset 50,331,904 B.
    int*  flag = (int*)ws;                        // 256 B
    bf16* xb   = (bf16*)(ws + 256);               // 8 MB
    bf16* wab  = (bf16*)(ws + 8388864);           // 6 MB
    bf16* wpb  = (bf16*)(ws + 14680320);          // 2 MB
    bf16* qkv  = (bf16*)(ws + 16777472);          // 25.2 MB
    bf16* yb   = (bf16*)(ws + 41943296);          // 8 MB -> end 50,331,904

    // convert + dtype detection fused, vectorized (float4 -> bf16x4)
    convert_detect_kernel<<<512, 256, 0, stream>>>(
        (const float*)d_in[0], (const float*)d_in[1], (const float*)d_in[3],
        xb, wab, wpb, flag);

    {   // qkv = x @ w_attn^T + b_attn (q pre-scaled); BN=64, 3-buf counted vmcnt
        dim3 grid(M / 128, 3072 / 64);    // 1536 blocks, %8==0
        gemm_nt_lds_t<2><<<grid, 256, 0, stream>>>(d_in[0], xb, d_in[1], wab,
                                                   d_in[2], qkv, M, 3072, 1024,
                                                   flag, 0, 1, 1);
    }
    {   // flash attention: round-5 proven kernel (8-wave, pairing, XCD)
        attn_mfma<<<512, 512, 0, stream>>>(qkv, yb);
    }
    {   // out = y @ w_proj^T + b_proj; BN=64, 3-buf counted vmcnt
        dim3 grid(M / 128, 1024 / 64);    // 512 blocks, %8==0
        gemm_nt_lds_t<2><<<grid, 256, 0, stream>>>(yb, yb, d_in[3], wpb,
                                                   d_in[4], d_out, M, 1024, 1024,
                                                   flag, 1, 0, 1);
    }
    (void)in_sizes; (void)n_in; (void)out_size; (void)ws_size;
}

// Round 15
// 177.098 us; speedup vs baseline: 1.0812x; 1.0812x over previous
//
#include <hip/hip_runtime.h>
#include <hip/hip_bf16.h>

using bf16 = __hip_bfloat16;

typedef __bf16 bf16x8 __attribute__((ext_vector_type(8)));
typedef __bf16 bf16x4v __attribute__((ext_vector_type(4)));
typedef float  float4v __attribute__((ext_vector_type(4)));
typedef unsigned short u16x8 __attribute__((ext_vector_type(8)));

#define MFMA16x16x32(a, b, c) __builtin_amdgcn_mfma_f32_16x16x32_bf16((a), (b), (c), 0, 0, 0)

#if __has_builtin(__builtin_amdgcn_exp2f)
#define EXP2F(x) __builtin_amdgcn_exp2f(x)
#else
#define EXP2F(x) exp2f(x)
#endif

#define T_SEQ 2048
#define NHEAD 16
#define CDIM  1024
#define HD3   3072

// async global->LDS, 16B per lane. LDS dest must be wave-uniform base + lane*16.
__device__ __forceinline__ void async_copy16(const void* g, void* l) {
    __builtin_amdgcn_global_load_lds(
        (__attribute__((address_space(1))) unsigned int*)g,
        (__attribute__((address_space(3))) unsigned int*)l,
        16, 0, 0);
}

// ---------------------------------------------------------------------------
// Convert + dtype detection, VECTORIZED (round-8 proven): float4 loads +
// bf16x4 stores, three branch-free per-region loops. Dedicated conversion
// reads x ONCE (fusing into gemm1 tripled its FETCH -- round 12). Each block
// re-detects (L2-hit); block 0 publishes flag[0]. flag=1 -> fp32 input.
// ---------------------------------------------------------------------------
__global__ __launch_bounds__(256) void convert_detect_kernel(
    const float* __restrict__ x, const float* __restrict__ wa,
    const float* __restrict__ wp,
    bf16* __restrict__ xb, bf16* __restrict__ wab, bf16* __restrict__ wpb,
    int* __restrict__ flag)
{
    __shared__ int red[256];
    const u16x8* xs8 = (const u16x8*)x;
    int cnt = 0;
    for (int i = threadIdx.x; i < 2048; i += 256) {
        const u16x8 v = xs8[i];
#pragma unroll
        for (int t = 0; t < 8; ++t) {
            const int e = (v[t] >> 7) & 0xFF;
            if (e == 0xFF || (e != 0 && e < 0x60)) cnt++;
        }
    }
    red[threadIdx.x] = cnt;
    __syncthreads();
    for (int s = 128; s > 0; s >>= 1) {
        if (threadIdx.x < s) red[threadIdx.x] += red[threadIdx.x + s];
        __syncthreads();
    }
    const int isf32 = (red[0] > 100) ? 1 : 0;
    if (blockIdx.x == 0 && threadIdx.x == 0) flag[0] = isf32;
    if (!isf32) return;

    const int gid    = blockIdx.x * 256 + threadIdx.x;
    const int stride = gridDim.x * 256;
    const float4v* x4  = (const float4v*)x;    // 1048576 float4
    const float4v* wa4 = (const float4v*)wa;   //  786432 float4
    const float4v* wp4 = (const float4v*)wp;   //  262144 float4
    bf16x4v* xb4  = (bf16x4v*)xb;
    bf16x4v* wab4 = (bf16x4v*)wab;
    bf16x4v* wpb4 = (bf16x4v*)wpb;

    for (int i = gid; i < 1048576; i += stride) {
        const float4v v = x4[i];
        bf16x4v o;
#pragma unroll
        for (int t = 0; t < 4; ++t) o[t] = (__bf16)v[t];
        xb4[i] = o;
    }
    for (int i = gid; i < 786432; i += stride) {
        const float4v v = wa4[i];
        bf16x4v o;
#pragma unroll
        for (int t = 0; t < 4; ++t) o[t] = (__bf16)v[t];
        wab4[i] = o;
    }
    for (int i = gid; i < 262144; i += stride) {
        const float4v v = wp4[i];
        bf16x4v o;
#pragma unroll
        for (int t = 0; t < 4; ++t) o[t] = (__bf16)v[t];
        wpb4[i] = o;
    }
}

// ---------------------------------------------------------------------------
// NT GEMM, BK=64, XOR-swizzled async staging, DOUBLE-BUFFERED LDS (round-10/
// 13 proven, 43.6 us @ gemm1): 2-phase k-loop {issue loads for k+1 into
// buf^1 || compute buf; one barrier}. 48KB LDS keeps 3 blocks/CU -- the
// round-14 3-buffer experiment (72KB, counted vmcnt) cut residency to 2 and
// L2 reuse with it (FETCH +48%, dur +34%): occupancy trap, m132 class.
// JF = per-wave N fragments (JF=2 -> BN=64). swz: bijective XCD remap.
// scale_q: multiply (acc+bias) by 0.125*log2e for cols < 1024 (q-columns).
// ---------------------------------------------------------------------------
template<int JF>
__global__ __launch_bounds__(256) void gemm_nt_lds_t(
    const void* __restrict__ Araw, const bf16* __restrict__ Aconv,
    const void* __restrict__ Braw, const bf16* __restrict__ Bconv,
    const void* __restrict__ biasraw, void* __restrict__ Cv,
    int M, int N, int K, const int* __restrict__ flag, int is_final,
    int scale_q, int swz)
{
    const bool f32 = (flag[0] != 0);
    const bf16* A = f32 ? Aconv : (const bf16*)Araw;
    const bf16* B = f32 ? Bconv : (const bf16*)Braw;

    __shared__ bf16 As[2][128 * 64];
    __shared__ bf16 Bs[2][JF * 32 * 64];

    const int tid  = threadIdx.x;
    const int lane = tid & 63;
    const int wave = tid >> 6;
    const int wm = wave & 1, wn = wave >> 1;
    const int c = lane & 15, g = lane >> 4;

    int bx = blockIdx.x, by = blockIdx.y;
    if (swz) {
        const int nwg = gridDim.x * gridDim.y;
        const int lin = by * gridDim.x + bx;
        const int nl  = (lin & 7) * (nwg >> 3) + (lin >> 3);
        bx = nl % gridDim.x;
        by = nl / gridDim.x;
    }
    const int bm = bx * 128;
    const int bn = by * (JF * 32);

    const int srow = tid >> 3;
    const int slc  = ((tid & 7) ^ (srow & 7)) * 8;
    const bf16* gA = A + (size_t)(bm + srow) * K + slc;
    const bf16* gB = B + (size_t)(bn + srow) * K + slc;

    float4v acc[4][JF] = {};

    // prologue: stage k0=0 into buf 0 (barrier drains vmcnt)
#pragma unroll
    for (int q = 0; q < 4; ++q)
        async_copy16(gA + (size_t)(q * 32) * K, &As[0][q * 2048 + tid * 8]);
#pragma unroll
    for (int q = 0; q < JF; ++q)
        async_copy16(gB + (size_t)(q * 32) * K, &Bs[0][q * 2048 + tid * 8]);
    __syncthreads();

    int b = 0;
    for (int k0 = 0; k0 < K; k0 += 64, b ^= 1) {
        // issue next tile into buf^1 (overlaps with compute below)
        if (k0 + 64 < K) {
#pragma unroll
            for (int q = 0; q < 4; ++q)
                async_copy16(gA + k0 + 64 + (size_t)(q * 32) * K,
                             &As[b ^ 1][q * 2048 + tid * 8]);
#pragma unroll
            for (int q = 0; q < JF; ++q)
                async_copy16(gB + k0 + 64 + (size_t)(q * 32) * K,
                             &Bs[b ^ 1][q * 2048 + tid * 8]);
        }

#pragma unroll
        for (int kk = 0; kk < 2; ++kk) {
            bf16x8 af[4], bfr[JF];
#pragma unroll
            for (int i = 0; i < 4; ++i)
                af[i]  = *(const bf16x8*)&As[b][(wm * 64 + i * 16 + c) * 64 +
                                               (((kk * 4 + g) ^ (c & 7)) * 8)];
#pragma unroll
            for (int j = 0; j < JF; ++j)
                bfr[j] = *(const bf16x8*)&Bs[b][(wn * (JF * 16) + j * 16 + c) * 64 +
                                               (((kk * 4 + g) ^ (c & 7)) * 8)];
#pragma unroll
            for (int i = 0; i < 4; ++i)
#pragma unroll
                for (int j = 0; j < JF; ++j)
                    acc[i][j] = MFMA16x16x32(af[i], bfr[j], acc[i][j]);
        }
        __syncthreads();   // drains this iter's loads; next iter reads buf^1
    }

    const bool f32o = is_final && f32;
    bf16*  Cb = (bf16*)Cv;
    float* Cf = (float*)Cv;

#pragma unroll
    for (int i = 0; i < 4; ++i) {
        const int row = bm + wm * 64 + i * 16 + g * 4;
#pragma unroll
        for (int j = 0; j < JF; ++j) {
            const int col = bn + wn * (JF * 16) + j * 16 + c;
            const float bv = f32 ? ((const float*)biasraw)[col]
                                 : __bfloat162float(((const bf16*)biasraw)[col]);
            const float sc = (scale_q && col < 1024) ? 0.18033688f : 1.0f;
            if (f32o) {
#pragma unroll
                for (int t = 0; t < 4; ++t)
                    Cf[(size_t)(row + t) * N + col] = (acc[i][j][t] + bv) * sc;
            } else {
#pragma unroll
                for (int t = 0; t < 4; ++t)
                    Cb[(size_t)(row + t) * N + col] =
                        __float2bfloat16((acc[i][j][t] + bv) * sc);
            }
        }
    }
}

// ---------------------------------------------------------------------------
// MFMA flash attention v9 (round-5/7/8/10/13 proven, unchanged): heavy/light
// pairing + bh->XCD locality, 8 waves x 16 queries per 128-q block (512
// threads). Staging role-split: waves 0-3 stage K (async), waves 4-7 stage V.
// ---------------------------------------------------------------------------
__global__ __launch_bounds__(512) void attn_mfma(
    const bf16* __restrict__ qkv, bf16* __restrict__ y)
{
    __shared__ __bf16 Ks[2][128 * 64];   // [buf][key][dim], chunk ^ (key&7)
    __shared__ __bf16 Vt[2][64 * 128];   // [buf][dim][kappa], chunk ^ (dim&7)

    const int tid  = threadIdx.x;
    const int lane = tid & 63;
    const int w    = tid >> 6;           // 0..7
    const int c    = lane & 15;
    const int g    = lane >> 4;

    // decode: i = role*256 + ((j*4 + bh_hi)<<3 | bh_lo); XCD = i%8 = bh&7
    const int i    = blockIdx.x;
    const int role = i >> 8;             // 0 = heavy, 1 = light
    const int bhl  = i & 7;
    const int t5   = (i & 255) >> 3;     // 0..31
    const int j    = t5 >> 2;            // 0..7
    const int bh   = ((t5 & 3) << 3) | bhl;
    const int qblk = role ? j : (15 - j);
    const int bb   = bh >> 4;
    const int h    = bh & 15;
    const size_t base = (size_t)bb * T_SEQ * HD3 + (size_t)h * 64;

    // staging indices (st = index within the staging half)
    const bool kstage = (tid < 256);
    const int st   = tid & 255;
    const int krow = st >> 3;                        // K: 0..31 (+ q*32)
    const int klc  = ((st & 7) ^ (krow & 7)) * 8;    // K: logical dim col
    const int kq   = st & 31;                        // V: key group
    const int dgv  = st >> 5;                        // V: dim group 0..7
    const int vchunk = (kq >> 3) * 4 + (kq & 3);
    const int vlow   = ((kq >> 2) & 1) * 4;

    const bf16* kgbase = qkv + base + 1024;
    const bf16* vgbase = qkv + base + 2048;

    bf16x8 ones;
#pragma unroll
    for (int ii = 0; ii < 8; ++ii) ones[ii] = (__bf16)1.0f;

    const int q0 = qblk * 128;
    const int qw = q0 + w * 16;          // wave query origin (16 q per wave)

    // Q B-fragment (pre-scaled by 0.125*log2e in gemm1 epilogue)
    bf16x8 qf[2];
#pragma unroll
    for (int kf2 = 0; kf2 < 2; ++kf2)
        qf[kf2] = *(const bf16x8*)(qkv + base
            + (size_t)(qw + c) * HD3 + kf2 * 32 + g * 8);

    float4v o[4] = {};
    float4v ol = {};                     // lsum via ones-MFMA

    // ---- prologue: stage tile 0 into buf 0 ----
    if (kstage) {
#pragma unroll
        for (int q = 0; q < 4; ++q)
            async_copy16(kgbase + (size_t)(q * 32 + krow) * HD3 + klc,
                         &Ks[0][q * 2048 + st * 8]);
    } else {
        bf16x8 vr[4];
#pragma unroll
        for (int r = 0; r < 4; ++r)
            vr[r] = *(const bf16x8*)(vgbase + (size_t)(kq * 4 + r) * HD3 + dgv * 8);
#pragma unroll
        for (int jj = 0; jj < 8; ++jj) {
            const int d = dgv * 8 + jj;
            bf16x4v pk;
#pragma unroll
            for (int r = 0; r < 4; ++r) pk[r] = vr[r][jj];
            *(bf16x4v*)&Vt[0][d * 128 + ((vchunk ^ (d & 7)) << 3) + vlow] = pk;
        }
    }
    __syncthreads();

    int b = 0;
    for (int kt = 0; kt <= q0; kt += 128, b ^= 1) {
        const bool more = (kt + 128 <= q0);
        bf16x8 vr[4];
        if (more) {
            if (kstage) {
#pragma unroll
                for (int q = 0; q < 4; ++q)
                    async_copy16(kgbase + (size_t)(kt + 128 + q * 32 + krow) * HD3 + klc,
                                 &Ks[b ^ 1][q * 2048 + st * 8]);
            } else {
#pragma unroll
                for (int r = 0; r < 4; ++r)
                    vr[r] = *(const bf16x8*)(vgbase + (size_t)(kt + 128 + kq * 4 + r) * HD3 + dgv * 8);
            }
        }

#pragma unroll
        for (int hf = 0; hf < 2; ++hf) {
            if (kt + hf * 64 > qw + 15) continue;   // whole half masked for wave

            // ---- S^T = K Q^T over 64 keys x 16 queries ----
            float4v sacc[4] = {};
            __builtin_amdgcn_s_setprio(1);
#pragma unroll
            for (int jb = 0; jb < 4; ++jb) {
                const int key = hf * 64 + jb * 16 + c;
                bf16x8 a0 = *(const bf16x8*)&Ks[b][key * 64 + ((g ^ (c & 7)) * 8)];
                bf16x8 a1 = *(const bf16x8*)&Ks[b][key * 64 + (((4 + g) ^ (c & 7)) * 8)];
                sacc[jb] = MFMA16x16x32(a0, qf[0], sacc[jb]);
                sacc[jb] = MFMA16x16x32(a1, qf[1], sacc[jb]);
            }
            __builtin_amdgcn_s_setprio(0);

            // ---- mask + exp2 + pack P (registers only) ----
            bf16x8 pf[2];
            {
                if (kt + hf * 64 + 63 > qw) {
                    const int query = qw + c;
#pragma unroll
                    for (int jb = 0; jb < 4; ++jb) {
                        const int kb = kt + hf * 64 + jb * 16 + g * 4;
#pragma unroll
                        for (int t = 0; t < 4; ++t)
                            if (kb + t > query) sacc[jb][t] = -1e30f;
                    }
                }
#pragma unroll
                for (int jb = 0; jb < 4; ++jb)
#pragma unroll
                    for (int t = 0; t < 4; ++t)
                        sacc[jb][t] = EXP2F(sacc[jb][t]);
#pragma unroll
                for (int lkf = 0; lkf < 2; ++lkf) {
                    bf16x8 pk;
#pragma unroll
                    for (int jj = 0; jj < 8; ++jj)
                        pk[jj] = (__bf16)sacc[lkf * 2 + (jj >> 2)][jj & 3];
                    pf[lkf] = pk;
                }
            }

            // ---- O^T += V^T P ; lsum += 1^T P (this half) ----
            __builtin_amdgcn_s_setprio(1);
#pragma unroll
            for (int lkf = 0; lkf < 2; ++lkf) {
                const int kf = hf * 2 + lkf;
                ol = MFMA16x16x32(ones, pf[lkf], ol);
#pragma unroll
                for (int dn = 0; dn < 4; ++dn) {
                    const int d = dn * 16 + c;
                    bf16x8 vf = *(const bf16x8*)
                        &Vt[b][d * 128 + (((kf * 4 + g) ^ (d & 7)) << 3)];
                    o[dn] = MFMA16x16x32(vf, pf[lkf], o[dn]);
                }
            }
            __builtin_amdgcn_s_setprio(0);
        }

        if (more && !kstage) {
#pragma unroll
            for (int jj = 0; jj < 8; ++jj) {
                const int d = dgv * 8 + jj;
                bf16x4v pk;
#pragma unroll
                for (int r = 0; r < 4; ++r) pk[r] = vr[r][jj];
                *(bf16x4v*)&Vt[b ^ 1][d * 128 + ((vchunk ^ (d & 7)) << 3) + vlow] = pk;
            }
        }
        __syncthreads();
    }

    // ---- store: lane holds query q (col c), dims dn*16+g*4+t ----
    {
        const float linv = 1.f / ol.x;
        const int q = qw + c;
        const size_t yb = ((size_t)bb * T_SEQ + q) * CDIM + h * 64;
#pragma unroll
        for (int dn = 0; dn < 4; ++dn) {
            bf16x4v ov;
#pragma unroll
            for (int t = 0; t < 4; ++t)
                ov[t] = (__bf16)(o[dn][t] * linv);
            *(bf16x4v*)&y[yb + dn * 16 + g * 4] = ov;
        }
    }
}

// ---------------------------------------------------------------------------
extern "C" void kernel_launch(void* const* d_in, const int* in_sizes, int n_in,
                              void* d_out, int out_size, void* d_ws, size_t ws_size,
                              hipStream_t stream)
{
    const int M = 4096;   // B*T
    char* ws = (char*)d_ws;

    // Footprint identical to the proven baseline: max offset 50,331,904 B.
    int*  flag = (int*)ws;                        // 256 B
    bf16* xb   = (bf16*)(ws + 256);               // 8 MB
    bf16* wab  = (bf16*)(ws + 8388864);           // 6 MB
    bf16* wpb  = (bf16*)(ws + 14680320);          // 2 MB
    bf16* qkv  = (bf16*)(ws + 16777472);          // 25.2 MB
    bf16* yb   = (bf16*)(ws + 41943296);          // 8 MB -> end 50,331,904

    // convert + dtype detection fused, vectorized (float4 -> bf16x4)
    convert_detect_kernel<<<512, 256, 0, stream>>>(
        (const float*)d_in[0], (const float*)d_in[1], (const float*)d_in[3],
        xb, wab, wpb, flag);

    {   // qkv = x @ w_attn^T + b_attn (q pre-scaled); BN=64, double-buffered
        dim3 grid(M / 128, 3072 / 64);    // 1536 blocks, %8==0
        gemm_nt_lds_t<2><<<grid, 256, 0, stream>>>(d_in[0], xb, d_in[1], wab,
                                                   d_in[2], qkv, M, 3072, 1024,
                                                   flag, 0, 1, 1);
    }
    {   // flash attention: round-5 proven kernel (8-wave, pairing, XCD)
        attn_mfma<<<512, 512, 0, stream>>>(qkv, yb);
    }
    {   // out = y @ w_proj^T + b_proj; BN=64, double-buffered
        dim3 grid(M / 128, 1024 / 64);    // 512 blocks, %8==0
        gemm_nt_lds_t<2><<<grid, 256, 0, stream>>>(yb, yb, d_in[3], wpb,
                                                   d_in[4], d_out, M, 1024, 1024,
                                                   flag, 1, 0, 1);
    }
    (void)in_sizes; (void)n_in; (void)out_size; (void)ws_size;
}

// Round 16
// 173.570 us; speedup vs baseline: 1.1032x; 1.0203x over previous
//
#include <hip/hip_runtime.h>
#include <hip/hip_bf16.h>

using bf16 = __hip_bfloat16;

typedef __bf16 bf16x8 __attribute__((ext_vector_type(8)));
typedef __bf16 bf16x4v __attribute__((ext_vector_type(4)));
typedef float  float4v __attribute__((ext_vector_type(4)));
typedef unsigned short u16x8 __attribute__((ext_vector_type(8)));

#define MFMA16x16x32(a, b, c) __builtin_amdgcn_mfma_f32_16x16x32_bf16((a), (b), (c), 0, 0, 0)

#if __has_builtin(__builtin_amdgcn_exp2f)
#define EXP2F(x) __builtin_amdgcn_exp2f(x)
#else
#define EXP2F(x) exp2f(x)
#endif

#define T_SEQ 2048
#define NHEAD 16
#define CDIM  1024
#define HD3   3072

// async global->LDS, 16B per lane. LDS dest must be wave-uniform base + lane*16.
__device__ __forceinline__ void async_copy16(const void* g, void* l) {
    __builtin_amdgcn_global_load_lds(
        (__attribute__((address_space(1))) unsigned int*)g,
        (__attribute__((address_space(3))) unsigned int*)l,
        16, 0, 0);
}

// ---------------------------------------------------------------------------
// Convert + dtype detection, VECTORIZED (round-8 proven): float4 loads +
// bf16x4 stores, three branch-free per-region loops. Dedicated conversion
// reads x ONCE (fusing into gemm1 tripled its FETCH -- round 12). Each block
// re-detects (L2-hit); block 0 publishes flag[0]. flag=1 -> fp32 input.
// Round-16: grid 512 -> 1536 blocks (was ~3.7 TB/s, memory-bound, needs
// more concurrency to approach the ~6.3 TB/s ceiling).
// ---------------------------------------------------------------------------
__global__ __launch_bounds__(256) void convert_detect_kernel(
    const float* __restrict__ x, const float* __restrict__ wa,
    const float* __restrict__ wp,
    bf16* __restrict__ xb, bf16* __restrict__ wab, bf16* __restrict__ wpb,
    int* __restrict__ flag)
{
    __shared__ int red[256];
    const u16x8* xs8 = (const u16x8*)x;
    int cnt = 0;
    for (int i = threadIdx.x; i < 2048; i += 256) {
        const u16x8 v = xs8[i];
#pragma unroll
        for (int t = 0; t < 8; ++t) {
            const int e = (v[t] >> 7) & 0xFF;
            if (e == 0xFF || (e != 0 && e < 0x60)) cnt++;
        }
    }
    red[threadIdx.x] = cnt;
    __syncthreads();
    for (int s = 128; s > 0; s >>= 1) {
        if (threadIdx.x < s) red[threadIdx.x] += red[threadIdx.x + s];
        __syncthreads();
    }
    const int isf32 = (red[0] > 100) ? 1 : 0;
    if (blockIdx.x == 0 && threadIdx.x == 0) flag[0] = isf32;
    if (!isf32) return;

    const int gid    = blockIdx.x * 256 + threadIdx.x;
    const int stride = gridDim.x * 256;
    const float4v* x4  = (const float4v*)x;    // 1048576 float4
    const float4v* wa4 = (const float4v*)wa;   //  786432 float4
    const float4v* wp4 = (const float4v*)wp;   //  262144 float4
    bf16x4v* xb4  = (bf16x4v*)xb;
    bf16x4v* wab4 = (bf16x4v*)wab;
    bf16x4v* wpb4 = (bf16x4v*)wpb;

    for (int i = gid; i < 1048576; i += stride) {
        const float4v v = x4[i];
        bf16x4v o;
#pragma unroll
        for (int t = 0; t < 4; ++t) o[t] = (__bf16)v[t];
        xb4[i] = o;
    }
    for (int i = gid; i < 786432; i += stride) {
        const float4v v = wa4[i];
        bf16x4v o;
#pragma unroll
        for (int t = 0; t < 4; ++t) o[t] = (__bf16)v[t];
        wab4[i] = o;
    }
    for (int i = gid; i < 262144; i += stride) {
        const float4v v = wp4[i];
        bf16x4v o;
#pragma unroll
        for (int t = 0; t < 4; ++t) o[t] = (__bf16)v[t];
        wpb4[i] = o;
    }
}

// ---------------------------------------------------------------------------
// NT GEMM, BK=64, XOR-swizzled async staging, DOUBLE-BUFFERED LDS (round-10/
// 13 proven, 43.6 us @ gemm1): 2-phase k-loop {issue loads for k+1 into
// buf^1 || compute buf; one barrier}. 48KB LDS keeps 3 blocks/CU (72KB
// 3-buffer cut residency and regressed 34% -- round 14, m132 class).
// Round-16 swizzle: 4x2 RECTANGULAR XCD tiling (gx==32 path). Old mapping
// gave each XCD ALL 32 bx x 6 by -> 8MB A working set, 2x L2 -> guaranteed
// A-panel misses (FETCH 4.9x ideal). New: XCD k owns 8 bx x (gy/2) by,
// bx-fast order -> A-resident 2MB (L2-fit), B streams. Bijective:
// (k>>1,t&7)<->bx, (k&1,t>>3)<->by.
// JF = per-wave N fragments (JF=2 -> BN=64). swz requires grid %8==0.
// scale_q: multiply (acc+bias) by 0.125*log2e for cols < 1024 (q-columns).
// ---------------------------------------------------------------------------
template<int JF>
__global__ __launch_bounds__(256) void gemm_nt_lds_t(
    const void* __restrict__ Araw, const bf16* __restrict__ Aconv,
    const void* __restrict__ Braw, const bf16* __restrict__ Bconv,
    const void* __restrict__ biasraw, void* __restrict__ Cv,
    int M, int N, int K, const int* __restrict__ flag, int is_final,
    int scale_q, int swz)
{
    const bool f32 = (flag[0] != 0);
    const bf16* A = f32 ? Aconv : (const bf16*)Araw;
    const bf16* B = f32 ? Bconv : (const bf16*)Braw;

    __shared__ bf16 As[2][128 * 64];
    __shared__ bf16 Bs[2][JF * 32 * 64];

    const int tid  = threadIdx.x;
    const int lane = tid & 63;
    const int wave = tid >> 6;
    const int wm = wave & 1, wn = wave >> 1;
    const int c = lane & 15, g = lane >> 4;

    int bx = blockIdx.x, by = blockIdx.y;
    if (swz) {
        const int lin = by * gridDim.x + bx;
        const int k = lin & 7;            // XCD (dispatch round-robin)
        const int t = lin >> 3;           // index within XCD's share
        if (gridDim.x == 32) {
            // 4x2 rectangles: 8 bx x (gy/2) by per XCD, bx-fast
            bx = ((k >> 1) << 3) + (t & 7);
            by = ((k & 1) ? (gridDim.y >> 1) : 0) + (t >> 3);
        } else {
            const int nwg = gridDim.x * gridDim.y;
            const int nl  = k * (nwg >> 3) + t;
            bx = nl % gridDim.x;
            by = nl / gridDim.x;
        }
    }
    const int bm = bx * 128;
    const int bn = by * (JF * 32);

    const int srow = tid >> 3;
    const int slc  = ((tid & 7) ^ (srow & 7)) * 8;
    const bf16* gA = A + (size_t)(bm + srow) * K + slc;
    const bf16* gB = B + (size_t)(bn + srow) * K + slc;

    float4v acc[4][JF] = {};

    // prologue: stage k0=0 into buf 0 (barrier drains vmcnt)
#pragma unroll
    for (int q = 0; q < 4; ++q)
        async_copy16(gA + (size_t)(q * 32) * K, &As[0][q * 2048 + tid * 8]);
#pragma unroll
    for (int q = 0; q < JF; ++q)
        async_copy16(gB + (size_t)(q * 32) * K, &Bs[0][q * 2048 + tid * 8]);
    __syncthreads();

    int b = 0;
    for (int k0 = 0; k0 < K; k0 += 64, b ^= 1) {
        // issue next tile into buf^1 (overlaps with compute below)
        if (k0 + 64 < K) {
#pragma unroll
            for (int q = 0; q < 4; ++q)
                async_copy16(gA + k0 + 64 + (size_t)(q * 32) * K,
                             &As[b ^ 1][q * 2048 + tid * 8]);
#pragma unroll
            for (int q = 0; q < JF; ++q)
                async_copy16(gB + k0 + 64 + (size_t)(q * 32) * K,
                             &Bs[b ^ 1][q * 2048 + tid * 8]);
        }

#pragma unroll
        for (int kk = 0; kk < 2; ++kk) {
            bf16x8 af[4], bfr[JF];
#pragma unroll
            for (int i = 0; i < 4; ++i)
                af[i]  = *(const bf16x8*)&As[b][(wm * 64 + i * 16 + c) * 64 +
                                               (((kk * 4 + g) ^ (c & 7)) * 8)];
#pragma unroll
            for (int j = 0; j < JF; ++j)
                bfr[j] = *(const bf16x8*)&Bs[b][(wn * (JF * 16) + j * 16 + c) * 64 +
                                               (((kk * 4 + g) ^ (c & 7)) * 8)];
#pragma unroll
            for (int i = 0; i < 4; ++i)
#pragma unroll
                for (int j = 0; j < JF; ++j)
                    acc[i][j] = MFMA16x16x32(af[i], bfr[j], acc[i][j]);
        }
        __syncthreads();   // drains this iter's loads; next iter reads buf^1
    }

    const bool f32o = is_final && f32;
    bf16*  Cb = (bf16*)Cv;
    float* Cf = (float*)Cv;

#pragma unroll
    for (int i = 0; i < 4; ++i) {
        const int row = bm + wm * 64 + i * 16 + g * 4;
#pragma unroll
        for (int j = 0; j < JF; ++j) {
            const int col = bn + wn * (JF * 16) + j * 16 + c;
            const float bv = f32 ? ((const float*)biasraw)[col]
                                 : __bfloat162float(((const bf16*)biasraw)[col]);
            const float sc = (scale_q && col < 1024) ? 0.18033688f : 1.0f;
            if (f32o) {
#pragma unroll
                for (int t = 0; t < 4; ++t)
                    Cf[(size_t)(row + t) * N + col] = (acc[i][j][t] + bv) * sc;
            } else {
#pragma unroll
                for (int t = 0; t < 4; ++t)
                    Cb[(size_t)(row + t) * N + col] =
                        __float2bfloat16((acc[i][j][t] + bv) * sc);
            }
        }
    }
}

// ---------------------------------------------------------------------------
// MFMA flash attention v9 (round-5/7/8/10/13/15 proven, unchanged): heavy/
// light pairing + bh->XCD locality, 8 waves x 16 queries per 128-q block
// (512 threads). Staging role-split: waves 0-3 stage K, waves 4-7 stage V.
// ---------------------------------------------------------------------------
__global__ __launch_bounds__(512) void attn_mfma(
    const bf16* __restrict__ qkv, bf16* __restrict__ y)
{
    __shared__ __bf16 Ks[2][128 * 64];   // [buf][key][dim], chunk ^ (key&7)
    __shared__ __bf16 Vt[2][64 * 128];   // [buf][dim][kappa], chunk ^ (dim&7)

    const int tid  = threadIdx.x;
    const int lane = tid & 63;
    const int w    = tid >> 6;           // 0..7
    const int c    = lane & 15;
    const int g    = lane >> 4;

    // decode: i = role*256 + ((j*4 + bh_hi)<<3 | bh_lo); XCD = i%8 = bh&7
    const int i    = blockIdx.x;
    const int role = i >> 8;             // 0 = heavy, 1 = light
    const int bhl  = i & 7;
    const int t5   = (i & 255) >> 3;     // 0..31
    const int j    = t5 >> 2;            // 0..7
    const int bh   = ((t5 & 3) << 3) | bhl;
    const int qblk = role ? j : (15 - j);
    const int bb   = bh >> 4;
    const int h    = bh & 15;
    const size_t base = (size_t)bb * T_SEQ * HD3 + (size_t)h * 64;

    // staging indices (st = index within the staging half)
    const bool kstage = (tid < 256);
    const int st   = tid & 255;
    const int krow = st >> 3;                        // K: 0..31 (+ q*32)
    const int klc  = ((st & 7) ^ (krow & 7)) * 8;    // K: logical dim col
    const int kq   = st & 31;                        // V: key group
    const int dgv  = st >> 5;                        // V: dim group 0..7
    const int vchunk = (kq >> 3) * 4 + (kq & 3);
    const int vlow   = ((kq >> 2) & 1) * 4;

    const bf16* kgbase = qkv + base + 1024;
    const bf16* vgbase = qkv + base + 2048;

    bf16x8 ones;
#pragma unroll
    for (int ii = 0; ii < 8; ++ii) ones[ii] = (__bf16)1.0f;

    const int q0 = qblk * 128;
    const int qw = q0 + w * 16;          // wave query origin (16 q per wave)

    // Q B-fragment (pre-scaled by 0.125*log2e in gemm1 epilogue)
    bf16x8 qf[2];
#pragma unroll
    for (int kf2 = 0; kf2 < 2; ++kf2)
        qf[kf2] = *(const bf16x8*)(qkv + base
            + (size_t)(qw + c) * HD3 + kf2 * 32 + g * 8);

    float4v o[4] = {};
    float4v ol = {};                     // lsum via ones-MFMA

    // ---- prologue: stage tile 0 into buf 0 ----
    if (kstage) {
#pragma unroll
        for (int q = 0; q < 4; ++q)
            async_copy16(kgbase + (size_t)(q * 32 + krow) * HD3 + klc,
                         &Ks[0][q * 2048 + st * 8]);
    } else {
        bf16x8 vr[4];
#pragma unroll
        for (int r = 0; r < 4; ++r)
            vr[r] = *(const bf16x8*)(vgbase + (size_t)(kq * 4 + r) * HD3 + dgv * 8);
#pragma unroll
        for (int jj = 0; jj < 8; ++jj) {
            const int d = dgv * 8 + jj;
            bf16x4v pk;
#pragma unroll
            for (int r = 0; r < 4; ++r) pk[r] = vr[r][jj];
            *(bf16x4v*)&Vt[0][d * 128 + ((vchunk ^ (d & 7)) << 3) + vlow] = pk;
        }
    }
    __syncthreads();

    int b = 0;
    for (int kt = 0; kt <= q0; kt += 128, b ^= 1) {
        const bool more = (kt + 128 <= q0);
        bf16x8 vr[4];
        if (more) {
            if (kstage) {
#pragma unroll
                for (int q = 0; q < 4; ++q)
                    async_copy16(kgbase + (size_t)(kt + 128 + q * 32 + krow) * HD3 + klc,
                                 &Ks[b ^ 1][q * 2048 + st * 8]);
            } else {
#pragma unroll
                for (int r = 0; r < 4; ++r)
                    vr[r] = *(const bf16x8*)(vgbase + (size_t)(kt + 128 + kq * 4 + r) * HD3 + dgv * 8);
            }
        }

#pragma unroll
        for (int hf = 0; hf < 2; ++hf) {
            if (kt + hf * 64 > qw + 15) continue;   // whole half masked for wave

            // ---- S^T = K Q^T over 64 keys x 16 queries ----
            float4v sacc[4] = {};
            __builtin_amdgcn_s_setprio(1);
#pragma unroll
            for (int jb = 0; jb < 4; ++jb) {
                const int key = hf * 64 + jb * 16 + c;
                bf16x8 a0 = *(const bf16x8*)&Ks[b][key * 64 + ((g ^ (c & 7)) * 8)];
                bf16x8 a1 = *(const bf16x8*)&Ks[b][key * 64 + (((4 + g) ^ (c & 7)) * 8)];
                sacc[jb] = MFMA16x16x32(a0, qf[0], sacc[jb]);
                sacc[jb] = MFMA16x16x32(a1, qf[1], sacc[jb]);
            }
            __builtin_amdgcn_s_setprio(0);

            // ---- mask + exp2 + pack P (registers only) ----
            bf16x8 pf[2];
            {
                if (kt + hf * 64 + 63 > qw) {
                    const int query = qw + c;
#pragma unroll
                    for (int jb = 0; jb < 4; ++jb) {
                        const int kb = kt + hf * 64 + jb * 16 + g * 4;
#pragma unroll
                        for (int t = 0; t < 4; ++t)
                            if (kb + t > query) sacc[jb][t] = -1e30f;
                    }
                }
#pragma unroll
                for (int jb = 0; jb < 4; ++jb)
#pragma unroll
                    for (int t = 0; t < 4; ++t)
                        sacc[jb][t] = EXP2F(sacc[jb][t]);
#pragma unroll
                for (int lkf = 0; lkf < 2; ++lkf) {
                    bf16x8 pk;
#pragma unroll
                    for (int jj = 0; jj < 8; ++jj)
                        pk[jj] = (__bf16)sacc[lkf * 2 + (jj >> 2)][jj & 3];
                    pf[lkf] = pk;
                }
            }

            // ---- O^T += V^T P ; lsum += 1^T P (this half) ----
            __builtin_amdgcn_s_setprio(1);
#pragma unroll
            for (int lkf = 0; lkf < 2; ++lkf) {
                const int kf = hf * 2 + lkf;
                ol = MFMA16x16x32(ones, pf[lkf], ol);
#pragma unroll
                for (int dn = 0; dn < 4; ++dn) {
                    const int d = dn * 16 + c;
                    bf16x8 vf = *(const bf16x8*)
                        &Vt[b][d * 128 + (((kf * 4 + g) ^ (d & 7)) << 3)];
                    o[dn] = MFMA16x16x32(vf, pf[lkf], o[dn]);
                }
            }
            __builtin_amdgcn_s_setprio(0);
        }

        if (more && !kstage) {
#pragma unroll
            for (int jj = 0; jj < 8; ++jj) {
                const int d = dgv * 8 + jj;
                bf16x4v pk;
#pragma unroll
                for (int r = 0; r < 4; ++r) pk[r] = vr[r][jj];
                *(bf16x4v*)&Vt[b ^ 1][d * 128 + ((vchunk ^ (d & 7)) << 3) + vlow] = pk;
            }
        }
        __syncthreads();
    }

    // ---- store: lane holds query q (col c), dims dn*16+g*4+t ----
    {
        const float linv = 1.f / ol.x;
        const int q = qw + c;
        const size_t yb = ((size_t)bb * T_SEQ + q) * CDIM + h * 64;
#pragma unroll
        for (int dn = 0; dn < 4; ++dn) {
            bf16x4v ov;
#pragma unroll
            for (int t = 0; t < 4; ++t)
                ov[t] = (__bf16)(o[dn][t] * linv);
            *(bf16x4v*)&y[yb + dn * 16 + g * 4] = ov;
        }
    }
}

// ---------------------------------------------------------------------------
extern "C" void kernel_launch(void* const* d_in, const int* in_sizes, int n_in,
                              void* d_out, int out_size, void* d_ws, size_t ws_size,
                              hipStream_t stream)
{
    const int M = 4096;   // B*T
    char* ws = (char*)d_ws;

    // Footprint identical to the proven baseline: max offset 50,331,904 B.
    int*  flag = (int*)ws;                        // 256 B
    bf16* xb   = (bf16*)(ws + 256);               // 8 MB
    bf16* wab  = (bf16*)(ws + 8388864);           // 6 MB
    bf16* wpb  = (bf16*)(ws + 14680320);          // 2 MB
    bf16* qkv  = (bf16*)(ws + 16777472);          // 25.2 MB
    bf16* yb   = (bf16*)(ws + 41943296);          // 8 MB -> end 50,331,904

    // convert + dtype detection fused, vectorized (float4 -> bf16x4)
    convert_detect_kernel<<<1536, 256, 0, stream>>>(
        (const float*)d_in[0], (const float*)d_in[1], (const float*)d_in[3],
        xb, wab, wpb, flag);

    {   // qkv = x @ w_attn^T + b_attn (q pre-scaled); BN=64, double-buffered,
        // rectangular XCD swizzle (A-panels L2-resident)
        dim3 grid(M / 128, 3072 / 64);    // 32 x 48 = 1536 blocks
        gemm_nt_lds_t<2><<<grid, 256, 0, stream>>>(d_in[0], xb, d_in[1], wab,
                                                   d_in[2], qkv, M, 3072, 1024,
                                                   flag, 0, 1, 1);
    }
    {   // flash attention: round-5 proven kernel (8-wave, pairing, XCD)
        attn_mfma<<<512, 512, 0, stream>>>(qkv, yb);
    }
    {   // out = y @ w_proj^T + b_proj; BN=64, double-buffered, rect swizzle
        dim3 grid(M / 128, 1024 / 64);    // 32 x 16 = 512 blocks
        gemm_nt_lds_t<2><<<grid, 256, 0, stream>>>(yb, yb, d_in[3], wpb,
                                                   d_in[4], d_out, M, 1024, 1024,
                                                   flag, 1, 0, 1);
    }
    (void)in_sizes; (void)n_in; (void)out_size; (void)ws_size;
}